// Round 15
// baseline (215.675 us; speedup 1.0000x reference)
//
#include <hip/hip_runtime.h>
#include <hip/hip_bf16.h>
#include <cstdint>
#include <cstddef>

// Problem constants
#define B_    8
#define H_    8
#define BH_   64
#define S_    976     // sequence length
#define SP_   992     // V^T row stride (shorts)
#define D_    64      // head dim
#define DM_   512     // d_model
#define L_    16      // max_len
#define H2_   61      // pooled conv height / q-tiles
#define KW_   25      // conv taps
#define EFF_  32      // effective (conv+pool) taps
#define XOFF  3997696 // x output elements = 8*976*512; attn follows
#define OSTR  68      // olds row stride (floats)

typedef __attribute__((ext_vector_type(8))) short bf16x8;
typedef __attribute__((ext_vector_type(4))) short bf16x4;
typedef __attribute__((ext_vector_type(4))) unsigned short u16x4;
typedef __attribute__((ext_vector_type(4))) float f32x4;

__device__ __forceinline__ unsigned short f2bfu(float f) {
    union { float f; unsigned u; } v; v.f = f;
    unsigned u = v.u;
    u += 0x7fffu + ((u >> 16) & 1u);   // round-to-nearest-even
    return (unsigned short)(u >> 16);
}
__device__ __forceinline__ unsigned packbf(float a, float b) {
    return (unsigned)f2bfu(a) | ((unsigned)f2bfu(b) << 16);
}
__device__ __forceinline__ float bflo(unsigned u) {
    union { unsigned u; float f; } v; v.u = u << 16; return v.f;
}
__device__ __forceinline__ float bfhi(unsigned u) {
    union { unsigned u; float f; } v; v.u = u & 0xffff0000u; return v.f;
}

// K=16 bf16 MFMA (verified end-to-end in round 7)
__device__ __forceinline__ f32x4 mfma16(bf16x4 a, bf16x4 b, f32x4 c) {
#if __has_builtin(__builtin_amdgcn_mfma_f32_16x16x16bf16_1k)
    return __builtin_amdgcn_mfma_f32_16x16x16bf16_1k(a, b, c, 0, 0, 0);
#else
    asm volatile("v_mfma_f32_16x16x16_bf16 %0, %1, %2, %0"
                 : "+v"(c) : "v"(a), "v"(b));
    return c;
#endif
}

// ---------------------------------------------------------------------------
// Kernel 1: projection, 4-way block split (grid 1536). Each block stages a
// 152-row x slice (9.7 KB) and computes 2 of the 8 output iterations ->
// 4x occupancy, 1/4 the per-thread serial LDS-load chain.
// ---------------------------------------------------------------------------
__global__ __launch_bounds__(256) void proj_kernel(
    const float* __restrict__ qin, const float* __restrict__ kin,
    const float* __restrict__ vin, const float* __restrict__ wq,
    const float* __restrict__ wk, const float* __restrict__ wv,
    short* __restrict__ qws, short* __restrict__ kws, short* __restrict__ vtws) {
    __shared__ float xl[152 * L_];   // 9.7 KB slice (global rows r0..r0+151)
    __shared__ float wl[32 * 32];    // folded weights
    int blk = blockIdx.x;            // grid = 16*8*4*3 = 1536
    int cg  = blk & 15;
    int b   = (blk >> 4) & 7;
    int q4  = (blk >> 7) & 3;        // iteration-pair slice
    int tz  = blk >> 9;
    const float* x    = (tz == 0) ? qin : (tz == 1) ? kin : vin;
    const float* wsrc = (tz == 0) ? wq  : (tz == 1) ? wk  : wv;

    int r0 = 128 * q4;               // global x row base of this slice
    const float4* xb4 = (const float4*)(x + b * DM_ * L_);
    float4* xl4 = (float4*)xl;
    float4 z4 = {0.f, 0.f, 0.f, 0.f};
    for (int i = threadIdx.x; i < 152 * 4; i += 256) {
        int gi = r0 * 4 + i;         // global float4 index (< 2048 live)
        xl4[i] = (gi < DM_ * 4) ? xb4[gi] : z4;
    }
    for (int i = threadIdx.x; i < 1024; i += 256) {
        int ci = i >> 5;
        int t  = i & 31;
        int c  = cg * 32 + ci;
        int jlo = (t - 24 > 0) ? t - 24 : 0;
        int jhi = (t < 7) ? t : 7;
        float s = 0.f;
        for (int jj = jlo; jj <= jhi; ++jj) s += wsrc[c * KW_ + (t - jj)];
        wl[i] = s * 0.125f;
    }
    __syncthreads();

    int c_local = threadIdx.x >> 3;          // 0..31
    int slot    = threadIdx.x & 7;           // 0..7
    int c       = cg * 32 + c_local;
    float wreg[EFF_];
    #pragma unroll
    for (int i = 0; i < EFF_; ++i) wreg[i] = wl[c_local * 32 + i];

    #pragma unroll
    for (int itl = 0; itl < 2; ++itl) {
        int it    = q4 * 2 + itl;            // 0..7
        int pt    = slot + it * 8;           // 0..63
        int h2b   = pt >> 2;                 // global h2-quad 0..15
        int h2b_l = (slot + 8 * itl) >> 2;   // local quad 0..3
        int l0    = (pt & 3) * 4;            // 0,4,8,12
        float acc[4][4];
        #pragma unroll
        for (int d = 0; d < 4; ++d)
            #pragma unroll
            for (int jj = 0; jj < 4; ++jj) acc[d][jj] = 0.f;
        const float* xp = &xl[(h2b_l * 32) * L_ + l0];
        #pragma unroll
        for (int k = 0; k < 56; ++k) {
            float4 xv = *(const float4*)(xp + k * L_);
            #pragma unroll
            for (int d = 0; d < 4; ++d) {
                int t = k - 8 * d;
                if (t >= 0 && t < EFF_) {
                    acc[d][0] = fmaf(xv.x, wreg[t], acc[d][0]);
                    acc[d][1] = fmaf(xv.y, wreg[t], acc[d][1]);
                    acc[d][2] = fmaf(xv.z, wreg[t], acc[d][2]);
                    acc[d][3] = fmaf(xv.w, wreg[t], acc[d][3]);
                }
            }
        }
        #pragma unroll
        for (int d = 0; d < 4; ++d) {
            int h2 = h2b * 4 + d;
            if (h2 < H2_) {
                int f0   = c * S_ + h2 * L_ + l0;
                int s    = f0 >> 9;
                int head = (f0 >> 6) & 7;
                int dh   = f0 & 63;           // multiple of 4, dh+3 < 64
                int bh   = b * H_ + head;
                if (tz == 2) {
                    #pragma unroll
                    for (int jj = 0; jj < 4; ++jj)
                        vtws[((size_t)bh * D_ + dh + jj) * SP_ + s] =
                            (short)f2bfu(acc[d][jj]);
                } else {
                    u16x4 u = { f2bfu(acc[d][0]), f2bfu(acc[d][1]),
                                f2bfu(acc[d][2]), f2bfu(acc[d][3]) };
                    short* dst = (tz == 0) ? qws : kws;
                    *(u16x4*)(void*)&dst[((size_t)bh * S_ + s) * D_ + dh] = u;
                }
            }
        }
    }
}

// ---------------------------------------------------------------------------
// Kernel 2: attention. One block per (bh, q-tile); 4 waves, BRANCHLESS
// 16-iteration key loop: w0/w1/w2 own tiles 0-15/16-31/32-47 (all live),
// w3 owns 48-60 + 3 clamped phantom iterations (loads re-read tile 60,
// e masked to 0 -> zero contribution everywhere). No guards in the loop ->
// compiler can pipeline loads across tiles. pp in REGISTERS (R6-best),
// PV via K=16 MFMA on packed registers (R7-verified), pass B = scattered
// NT stores (R6-best write path).
// ---------------------------------------------------------------------------
__global__ __launch_bounds__(256) void attn_kernel(
    const short* __restrict__ qws, const short* __restrict__ kws,
    const short* __restrict__ vtws, const float* __restrict__ w_out,
    const float* __restrict__ b_out, float* __restrict__ out) {
    __shared__ float olds[4][16 * OSTR];      // 17.4 KB
    __shared__ float sums[4][16];
    __shared__ float inv16[16];

    int w    = threadIdx.x >> 6;
    int lane = threadIdx.x & 63;
    int l16  = lane & 15;
    int g    = lane >> 4;

    // XCD swizzle: xcd = blk%8 hosts bh in {xcd, xcd+8, ..., xcd+56}
    int blk = blockIdx.x;       // 0..3903
    int xcd = blk & 7;
    int j   = blk >> 3;         // 0..487
    int bh  = xcd + 8 * (j / H2_);
    int qt  = j % H2_;          // 0..60
    int s0  = qt * 16;

    int t0 = w * 16;            // tiles t0..t0+15 (w3: 48..63, 61+ phantom)

    const short* qb = qws + ((size_t)bh * S_ + s0 + l16) * D_ + g * 8;
    bf16x8 q0 = *(const bf16x8*)qb;
    bf16x8 q1 = *(const bf16x8*)(qb + 32);
    const short* kbase = kws + ((size_t)bh * S_ + l16) * D_ + g * 8;
    const short* vbase = vtws + ((size_t)bh * D_ + l16) * SP_ + g * 4;

    unsigned pp[16][2];         // packed bf16 exp-scores, register-resident
    f32x4 o0 = {0.f,0.f,0.f,0.f}, o1 = {0.f,0.f,0.f,0.f};
    f32x4 o2 = {0.f,0.f,0.f,0.f}, o3 = {0.f,0.f,0.f,0.f};
    float sa = 0.f, sb = 0.f, sc_ = 0.f, sd = 0.f;

    #pragma unroll
    for (int ct = 0; ct < 16; ++ct) {
        int gt  = t0 + ct;
        int gtc = (gt > 60) ? 60 : gt;        // clamp phantom tiles
        const short* kb = kbase + (size_t)gtc * 16 * D_;
        bf16x8 k0 = *(const bf16x8*)kb;
        bf16x8 k1 = *(const bf16x8*)(kb + 32);
        const short* vb = vbase + gtc * 16;
        bf16x4 v0 = *(const bf16x4*)(vb);
        bf16x4 v1 = *(const bf16x4*)(vb + 16 * SP_);
        bf16x4 v2 = *(const bf16x4*)(vb + 32 * SP_);
        bf16x4 v3 = *(const bf16x4*)(vb + 48 * SP_);
        f32x4 acc = {0.f, 0.f, 0.f, 0.f};
        acc = __builtin_amdgcn_mfma_f32_16x16x32_bf16(k0, q0, acc, 0, 0, 0);
        acc = __builtin_amdgcn_mfma_f32_16x16x32_bf16(k1, q1, acc, 0, 0, 0);
        bool live = (gt <= 60);               // mask phantom -> exact zeros
        float e0 = live ? __expf(acc[0] * 0.125f) : 0.f;
        float e1 = live ? __expf(acc[1] * 0.125f) : 0.f;
        float e2 = live ? __expf(acc[2] * 0.125f) : 0.f;
        float e3 = live ? __expf(acc[3] * 0.125f) : 0.f;
        sa += e0; sb += e1; sc_ += e2; sd += e3;
        unsigned u0 = packbf(e0, e1);
        unsigned u1 = packbf(e2, e3);
        pp[ct][0] = u0;
        pp[ct][1] = u1;
        union { uint2 u; bf16x4 v; } pc;
        pc.u.x = u0; pc.u.y = u1;
        o0 = mfma16(pc.v, v0, o0);
        o1 = mfma16(pc.v, v1, o1);
        o2 = mfma16(pc.v, v2, o2);
        o3 = mfma16(pc.v, v3, o3);
    }
    float sum = (sa + sb) + (sc_ + sd);
    sum += __shfl_xor(sum, 16);
    sum += __shfl_xor(sum, 32);
    if (lane < 16) sums[w][l16] = sum;
    __syncthreads();
    if (threadIdx.x < 16) {
        int r = threadIdx.x;
        inv16[r] = 1.f / ((sums[0][r] + sums[1][r]) +
                          (sums[2][r] + sums[3][r]));
    }
    __syncthreads();

    // ---- pass B: scattered NT stores straight from register pp ----
    {
        float invr = inv16[l16];
        float* arow = out + XOFF + ((size_t)bh * S_ + s0 + l16) * S_;
        #pragma unroll
        for (int ct = 0; ct < 16; ++ct) {
            int gt = t0 + ct;
            if (gt <= 60) {                   // wave-uniform (skip phantom)
                unsigned u0 = pp[ct][0], u1 = pp[ct][1];
                f32x4 pv = { bflo(u0) * invr, bfhi(u0) * invr,
                             bflo(u1) * invr, bfhi(u1) * invr };
                __builtin_nontemporal_store(pv,
                    (f32x4*)(arow + gt * 16 + g * 4));
            }
        }
    }

    // ---- all waves publish raw partial O ----
    {
        float* ob = &olds[w][0];
        #pragma unroll
        for (int i = 0; i < 4; ++i) {
            int q = g * 4 + i;
            ob[q * OSTR +  0 + l16] = o0[i];
            ob[q * OSTR + 16 + l16] = o1[i];
            ob[q * OSTR + 32 + l16] = o2[i];
            ob[q * OSTR + 48 + l16] = o3[i];
        }
    }
    __syncthreads();

    // ---- cooperative x epilogue: wave w writes rows 4w..4w+3 (256B each) ----
    {
        float wo = w_out[0], bo = b_out[0];
        int b = bh >> 3, hh = bh & 7;
        #pragma unroll
        for (int rr = 0; rr < 4; ++rr) {
            int r = w * 4 + rr;
            float s1 = inv16[r] * wo;
            int o = r * OSTR + lane;
            float v = olds[0][o] + olds[1][o] + olds[2][o] + olds[3][o];
            out[((size_t)b * S_ + s0 + r) * DM_ + hh * D_ + lane] = v * s1 + bo;
        }
    }
}

// ---------------------------------------------------------------------------
extern "C" void kernel_launch(void* const* d_in, const int* in_sizes, int n_in,
                              void* d_out, int out_size, void* d_ws, size_t ws_size,
                              hipStream_t stream) {
    const float* q   = (const float*)d_in[0];
    const float* k   = (const float*)d_in[1];
    const float* v   = (const float*)d_in[2];
    const float* wq  = (const float*)d_in[3];
    const float* wk  = (const float*)d_in[4];
    const float* wv  = (const float*)d_in[5];
    const float* wo  = (const float*)d_in[6];
    const float* bo  = (const float*)d_in[7];

    char* ws = (char*)d_ws;
    short* qws  = (short*)(ws + 196608);
    short* kws  = qws + (size_t)BH_ * S_ * D_;
    short* vtws = kws + (size_t)BH_ * S_ * D_;

    proj_kernel<<<1536, 256, 0, stream>>>(q, k, v, wq, wk, wv, qws, kws, vtws);
    attn_kernel<<<BH_ * H2_, 256, 0, stream>>>(qws, kws, vtws, wo, bo,
                                               (float*)d_out);
}

// Round 16
// 169.353 us; speedup vs baseline: 1.2735x; 1.2735x over previous
//
#include <hip/hip_runtime.h>
#include <hip/hip_bf16.h>
#include <cstdint>
#include <cstddef>

// Problem constants
#define B_    8
#define H_    8
#define BH_   64
#define S_    976     // sequence length
#define SP_   992     // V^T row stride (shorts)
#define D_    64      // head dim
#define DM_   512     // d_model
#define L_    16      // max_len
#define H2_   61      // pooled conv height / q-tiles
#define KW_   25      // conv taps
#define EFF_  32      // effective (conv+pool) taps
#define XOFF  3997696 // x output elements = 8*976*512; attn follows
#define OSTR  68      // olds row stride (floats)

typedef __attribute__((ext_vector_type(8))) short bf16x8;
typedef __attribute__((ext_vector_type(4))) unsigned short u16x4;
typedef __attribute__((ext_vector_type(4))) float f32x4;

__device__ __forceinline__ unsigned short f2bfu(float f) {
    union { float f; unsigned u; } v; v.f = f;
    unsigned u = v.u;
    u += 0x7fffu + ((u >> 16) & 1u);   // round-to-nearest-even
    return (unsigned short)(u >> 16);
}
__device__ __forceinline__ unsigned packbf(float a, float b) {
    return (unsigned)f2bfu(a) | ((unsigned)f2bfu(b) << 16);
}
__device__ __forceinline__ float bflo(unsigned u) {
    union { unsigned u; float f; } v; v.u = u << 16; return v.f;
}
__device__ __forceinline__ float bfhi(unsigned u) {
    union { unsigned u; float f; } v; v.u = u & 0xffff0000u; return v.f;
}

// ---------------------------------------------------------------------------
// Kernel 1: projection, task-split (grid 768 = 16cg x 8b x 2half x 3tz).
// Each block stages the full x[b] (34.3 KB) + inline-folds 32 channels'
// conv(25)+avgpool(8) weights, then computes HALF the output iterations
// (4 of 8) -> 2x blocks/CU vs R6, zero redundant FMA. float4 LDS reads,
// ushort4 q/k stores (R13-proven).
// ---------------------------------------------------------------------------
__global__ __launch_bounds__(256) void proj_kernel(
    const float* __restrict__ qin, const float* __restrict__ kin,
    const float* __restrict__ vin, const float* __restrict__ wq,
    const float* __restrict__ wk, const float* __restrict__ wv,
    short* __restrict__ qws, short* __restrict__ kws, short* __restrict__ vtws) {
    __shared__ float xl[536 * L_];   // 34.3 KB (rows 512..535 zero)
    __shared__ float wl[32 * 32];    // folded weights
    int blk  = blockIdx.x;           // grid = 768
    int cg   = blk & 15;
    int b    = (blk >> 4) & 7;
    int half = (blk >> 7) & 1;
    int tz   = blk >> 8;             // 0..2
    const float* x    = (tz == 0) ? qin : (tz == 1) ? kin : vin;
    const float* wsrc = (tz == 0) ? wq  : (tz == 1) ? wk  : wv;

    const float4* xb4 = (const float4*)(x + b * DM_ * L_);
    float4* xl4 = (float4*)xl;
    for (int i = threadIdx.x; i < DM_ * L_ / 4; i += 256) xl4[i] = xb4[i];
    for (int i = DM_ * L_ + threadIdx.x; i < 536 * L_; i += 256) xl[i] = 0.f;

    // fold conv(25)+avgpool(8) -> 32 taps for this block's 32 channels
    for (int i = threadIdx.x; i < 1024; i += 256) {
        int ci = i >> 5;
        int t  = i & 31;
        int c  = cg * 32 + ci;
        int jlo = (t - 24 > 0) ? t - 24 : 0;
        int jhi = (t < 7) ? t : 7;
        float s = 0.f;
        for (int jj = jlo; jj <= jhi; ++jj) s += wsrc[c * KW_ + (t - jj)];
        wl[i] = s * 0.125f;
    }
    __syncthreads();

    int c_local = threadIdx.x >> 3;          // 0..31
    int slot    = threadIdx.x & 7;           // 0..7
    int c       = cg * 32 + c_local;
    float wreg[EFF_];
    #pragma unroll
    for (int i = 0; i < EFF_; ++i) wreg[i] = wl[c_local * 32 + i];

    #pragma unroll
    for (int itl = 0; itl < 4; ++itl) {
        int it  = half * 4 + itl;            // 0..7
        int pt  = slot + it * 8;             // 0..63
        int h2b = pt >> 2;                   // h2-quad 0..15
        int l0  = (pt & 3) * 4;              // 0,4,8,12
        float acc[4][4];
        #pragma unroll
        for (int d = 0; d < 4; ++d)
            #pragma unroll
            for (int jj = 0; jj < 4; ++jj) acc[d][jj] = 0.f;
        const float* xp = &xl[(h2b * 32) * L_ + l0];
        #pragma unroll
        for (int k = 0; k < 56; ++k) {
            float4 xv = *(const float4*)(xp + k * L_);
            #pragma unroll
            for (int d = 0; d < 4; ++d) {
                int t = k - 8 * d;
                if (t >= 0 && t < EFF_) {
                    acc[d][0] = fmaf(xv.x, wreg[t], acc[d][0]);
                    acc[d][1] = fmaf(xv.y, wreg[t], acc[d][1]);
                    acc[d][2] = fmaf(xv.z, wreg[t], acc[d][2]);
                    acc[d][3] = fmaf(xv.w, wreg[t], acc[d][3]);
                }
            }
        }
        #pragma unroll
        for (int d = 0; d < 4; ++d) {
            int h2 = h2b * 4 + d;
            if (h2 < H2_) {
                int f0   = c * S_ + h2 * L_ + l0;
                int s    = f0 >> 9;
                int head = (f0 >> 6) & 7;
                int dh   = f0 & 63;           // multiple of 4, dh+3 < 64
                int bh   = b * H_ + head;
                if (tz == 2) {
                    #pragma unroll
                    for (int jj = 0; jj < 4; ++jj)
                        vtws[((size_t)bh * D_ + dh + jj) * SP_ + s] =
                            (short)f2bfu(acc[d][jj]);
                } else {
                    u16x4 u = { f2bfu(acc[d][0]), f2bfu(acc[d][1]),
                                f2bfu(acc[d][2]), f2bfu(acc[d][3]) };
                    short* dst = (tz == 0) ? qws : kws;
                    *(u16x4*)(void*)&dst[((size_t)bh * S_ + s) * D_ + dh] = u;
                }
            }
        }
    }
}

// ---------------------------------------------------------------------------
// Kernel 2: attention -- EXACT Round-6 structure (best measured: attn ~126us).
// One block per (bh, q-tile); 4 waves own key quarters (16/15/15/15).
// Pass A: QK^T (K=32, swapped) -> exp -> pack bf16 into pp[16][2] registers
// + partial sums. Pass B: NT attn writes from pp + PV via plds repack and
// K=32 MFMA (phantom zero-P half-chunk finishes odd tile counts; V-pad
// garbage is multiplied by zero P). olds combine; w3 writes x.
// ---------------------------------------------------------------------------
__global__ __launch_bounds__(256) void attn_kernel(
    const short* __restrict__ qws, const short* __restrict__ kws,
    const short* __restrict__ vtws, const float* __restrict__ w_out,
    const float* __restrict__ b_out, float* __restrict__ out) {
    __shared__ short plds[4][16 * 40];        // per-wave P repack (5 KB)
    __shared__ float olds[3][16 * OSTR];      // partial-O publish (13 KB)
    __shared__ float sums[4][16];

    int w    = threadIdx.x >> 6;
    int lane = threadIdx.x & 63;
    int l16  = lane & 15;
    int g    = lane >> 4;

    // XCD swizzle: xcd = blk%8 hosts bh in {xcd, xcd+8, ..., xcd+56}
    int blk = blockIdx.x;       // 0..3903
    int xcd = blk & 7;
    int j   = blk >> 3;         // 0..487
    int bh  = xcd + 8 * (j / H2_);
    int qt  = j % H2_;          // 0..60
    int s0  = qt * 16;

    int t0 = (w == 0) ? 0 : 16 + (w - 1) * 15;   // 0,16,31,46
    int nt = (w == 0) ? 16 : 15;

    unsigned pp[16][2];         // packed bf16 exp-scores, register-resident

    const short* qb = qws + ((size_t)bh * S_ + s0 + l16) * D_ + g * 8;
    bf16x8 q0 = *(const bf16x8*)qb;
    bf16x8 q1 = *(const bf16x8*)(qb + 32);
    const short* kb0 = kws + ((size_t)bh * S_ + t0 * 16 + l16) * D_ + g * 8;

    // ---- pass A: QK^T -> exp -> pack + partial sums ----
    float sa = 0.f, sb = 0.f, sc_ = 0.f, sd = 0.f;
    #pragma unroll
    for (int ct = 0; ct < 16; ++ct) {
        if (ct < nt) {                       // wave-uniform guard
            const short* kb = kb0 + (size_t)ct * 16 * D_;
            bf16x8 k0 = *(const bf16x8*)kb;
            bf16x8 k1 = *(const bf16x8*)(kb + 32);
            f32x4 acc = {0.f, 0.f, 0.f, 0.f};
            acc = __builtin_amdgcn_mfma_f32_16x16x32_bf16(k0, q0, acc, 0, 0, 0);
            acc = __builtin_amdgcn_mfma_f32_16x16x32_bf16(k1, q1, acc, 0, 0, 0);
            float e0 = __expf(acc[0] * 0.125f);
            float e1 = __expf(acc[1] * 0.125f);
            float e2 = __expf(acc[2] * 0.125f);
            float e3 = __expf(acc[3] * 0.125f);
            sa += e0; sb += e1; sc_ += e2; sd += e3;
            pp[ct][0] = packbf(e0, e1);
            pp[ct][1] = packbf(e2, e3);
        }
    }
    float sum = (sa + sb) + (sc_ + sd);
    sum += __shfl_xor(sum, 16);
    sum += __shfl_xor(sum, 32);
    if (lane < 16) sums[w][l16] = sum;
    __syncthreads();
    float inv = 1.f / ((sums[0][l16] + sums[1][l16]) +
                       (sums[2][l16] + sums[3][l16]));

    f32x4 o0 = {0.f,0.f,0.f,0.f}, o1 = {0.f,0.f,0.f,0.f};
    f32x4 o2 = {0.f,0.f,0.f,0.f}, o3 = {0.f,0.f,0.f,0.f};

    float* arow = out + XOFF + ((size_t)bh * S_ + s0 + l16) * S_;
    short* pl = &plds[w][0];
    const short* vrow = vtws + ((size_t)bh * D_ + l16) * SP_ + g * 8;

    // ---- pass B: full chunks (2 tiles each); w0 has 8, others 7+tail ----
    int nc = (w == 0) ? 8 : 7;
    #pragma unroll
    for (int c = 0; c < 8; ++c) {
        if (c < nc) {
            #pragma unroll
            for (int t = 0; t < 2; ++t) {
                int lt = 2 * c + t;            // static after unroll
                int gt = t0 + lt;
                unsigned u0 = pp[lt][0], u1 = pp[lt][1];
                f32x4 pv = { bflo(u0) * inv, bfhi(u0) * inv,
                             bflo(u1) * inv, bfhi(u1) * inv };
                __builtin_nontemporal_store(pv, (f32x4*)(arow + gt * 16 + g * 4));
                uint2 upk = {u0, u1};
                *(uint2*)(void*)(pl + l16 * 40 + t * 16 + g * 4) = upk;
            }
            __threadfence_block();
            bf16x8 pa = *(const bf16x8*)(pl + l16 * 40 + g * 8);
            const short* vb = vrow + t0 * 16 + c * 32;
            o0 = __builtin_amdgcn_mfma_f32_16x16x32_bf16(pa, *(const bf16x8*)(vb), o0, 0, 0, 0);
            o1 = __builtin_amdgcn_mfma_f32_16x16x32_bf16(pa, *(const bf16x8*)(vb + 16 * SP_), o1, 0, 0, 0);
            o2 = __builtin_amdgcn_mfma_f32_16x16x32_bf16(pa, *(const bf16x8*)(vb + 32 * SP_), o2, 0, 0, 0);
            o3 = __builtin_amdgcn_mfma_f32_16x16x32_bf16(pa, *(const bf16x8*)(vb + 48 * SP_), o3, 0, 0, 0);
        }
    }

    // ---- tail: odd 15th tile for w>0, phantom zero-P upper half ----
    if (w != 0) {
        unsigned u0 = pp[14][0], u1 = pp[14][1];
        f32x4 pv = { bflo(u0) * inv, bfhi(u0) * inv,
                     bflo(u1) * inv, bfhi(u1) * inv };
        __builtin_nontemporal_store(pv, (f32x4*)(arow + (t0 + 14) * 16 + g * 4));
        uint2 upk = {u0, u1};
        *(uint2*)(void*)(pl + l16 * 40 + g * 4) = upk;
        uint2 zz = {0u, 0u};
        *(uint2*)(void*)(pl + l16 * 40 + 16 + g * 4) = zz;   // P=0 -> no contrib
        __threadfence_block();
        bf16x8 pa = *(const bf16x8*)(pl + l16 * 40 + g * 8);
        const short* vb = vrow + t0 * 16 + 224;              // keys t0*16+224..+255
        o0 = __builtin_amdgcn_mfma_f32_16x16x32_bf16(pa, *(const bf16x8*)(vb), o0, 0, 0, 0);
        o1 = __builtin_amdgcn_mfma_f32_16x16x32_bf16(pa, *(const bf16x8*)(vb + 16 * SP_), o1, 0, 0, 0);
        o2 = __builtin_amdgcn_mfma_f32_16x16x32_bf16(pa, *(const bf16x8*)(vb + 32 * SP_), o2, 0, 0, 0);
        o3 = __builtin_amdgcn_mfma_f32_16x16x32_bf16(pa, *(const bf16x8*)(vb + 48 * SP_), o3, 0, 0, 0);
    }

    // ---- waves 0..2 publish raw partial O ----
    if (w != 3) {
        float* ob = &olds[w][0];
        #pragma unroll
        for (int i = 0; i < 4; ++i) {
            int q = g * 4 + i;
            ob[q * OSTR +  0 + l16] = o0[i];
            ob[q * OSTR + 16 + l16] = o1[i];
            ob[q * OSTR + 32 + l16] = o2[i];
            ob[q * OSTR + 48 + l16] = o3[i];
        }
    }
    __syncthreads();

    // ---- w3 combines, normalizes (deferred inv), writes x ----
    if (w == 3) {
        float wo = w_out[0], bo = b_out[0];
        int b = bh >> 3, hh = bh & 7;
        #pragma unroll
        for (int i = 0; i < 4; ++i) {
            int q = g * 4 + i;
            float invr = __shfl(inv, q);       // inv of query row q
            float s1 = invr * wo;
            float* xr = out + ((size_t)b * S_ + s0 + q) * DM_ + hh * D_ + l16;
            int o = q * OSTR + l16;
            xr[0]  = (o0[i] + olds[0][o +  0] + olds[1][o +  0] + olds[2][o +  0]) * s1 + bo;
            xr[16] = (o1[i] + olds[0][o + 16] + olds[1][o + 16] + olds[2][o + 16]) * s1 + bo;
            xr[32] = (o2[i] + olds[0][o + 32] + olds[1][o + 32] + olds[2][o + 32]) * s1 + bo;
            xr[48] = (o3[i] + olds[0][o + 48] + olds[1][o + 48] + olds[2][o + 48]) * s1 + bo;
        }
    }
}

// ---------------------------------------------------------------------------
extern "C" void kernel_launch(void* const* d_in, const int* in_sizes, int n_in,
                              void* d_out, int out_size, void* d_ws, size_t ws_size,
                              hipStream_t stream) {
    const float* q   = (const float*)d_in[0];
    const float* k   = (const float*)d_in[1];
    const float* v   = (const float*)d_in[2];
    const float* wq  = (const float*)d_in[3];
    const float* wk  = (const float*)d_in[4];
    const float* wv  = (const float*)d_in[5];
    const float* wo  = (const float*)d_in[6];
    const float* bo  = (const float*)d_in[7];

    char* ws = (char*)d_ws;
    short* qws  = (short*)(ws + 196608);
    short* kws  = qws + (size_t)BH_ * S_ * D_;
    short* vtws = kws + (size_t)BH_ * S_ * D_;

    proj_kernel<<<768, 256, 0, stream>>>(q, k, v, wq, wk, wv, qws, kws, vtws);
    attn_kernel<<<BH_ * H2_, 256, 0, stream>>>(qws, kws, vtws, wo, bo,
                                               (float*)d_out);
}

// Round 17
// 152.135 us; speedup vs baseline: 1.4177x; 1.1132x over previous
//
#include <hip/hip_runtime.h>
#include <hip/hip_bf16.h>
#include <cstdint>
#include <cstddef>

// Problem constants
#define B_    8
#define H_    8
#define BH_   64
#define S_    976     // sequence length
#define SP_   992     // V^T row stride (shorts)
#define D_    64      // head dim
#define DM_   512     // d_model
#define L_    16      // max_len
#define H2_   61      // pooled conv height / q-tiles
#define KW_   25      // conv taps
#define EFF_  32      // effective (conv+pool) taps
#define XOFF  3997696 // x output elements = 8*976*512; attn follows
#define NWB   49152   // 3*512*32 wbar elements
#define OSTR  68      // olds row stride (floats)

typedef __attribute__((ext_vector_type(8))) short bf16x8;
typedef __attribute__((ext_vector_type(4))) float f32x4;

__device__ __forceinline__ unsigned short f2bfu(float f) {
    union { float f; unsigned u; } v; v.f = f;
    unsigned u = v.u;
    u += 0x7fffu + ((u >> 16) & 1u);   // round-to-nearest-even
    return (unsigned short)(u >> 16);
}
__device__ __forceinline__ unsigned packbf(float a, float b) {
    return (unsigned)f2bfu(a) | ((unsigned)f2bfu(b) << 16);
}
__device__ __forceinline__ float bflo(unsigned u) {
    union { unsigned u; float f; } v; v.u = u << 16; return v.f;
}
__device__ __forceinline__ float bfhi(unsigned u) {
    union { unsigned u; float f; } v; v.u = u & 0xffff0000u; return v.f;
}

// ---------------------------------------------------------------------------
// Kernel 1: fold conv(25)+avgpool(8) into 32-tap filter; spare blocks zero
// the V^T pad columns (s=976..991).  (R6-exact)
// ---------------------------------------------------------------------------
__global__ __launch_bounds__(256) void wbar_kernel(
    const float* __restrict__ wq, const float* __restrict__ wk,
    const float* __restrict__ wv, float* __restrict__ wbar,
    short* __restrict__ vtws) {
    int idx = blockIdx.x * 256 + threadIdx.x;
    if (idx < NWB) {
        int t  = idx & 31;
        int c  = (idx >> 5) & 511;
        int tz = idx >> 14;
        const float* w = (tz == 0) ? wq : (tz == 1) ? wk : wv;
        int jlo = (t - 24 > 0) ? t - 24 : 0;
        int jhi = (t < 7) ? t : 7;
        float s = 0.f;
        for (int j = jlo; j <= jhi; ++j) s += w[c * KW_ + (t - j)];
        wbar[idx] = s * 0.125f;
    } else {
        int p = idx - NWB;                 // 0..65535
        int bh = p >> 10;
        int dh = (p >> 4) & 63;
        int s  = S_ + (p & 15);
        vtws[((size_t)bh * D_ + dh) * SP_ + s] = 0;
    }
}

// ---------------------------------------------------------------------------
// Kernel 2: projection, register-blocked (R6-exact).
// ---------------------------------------------------------------------------
__global__ __launch_bounds__(256) void proj_kernel(
    const float* __restrict__ qin, const float* __restrict__ kin,
    const float* __restrict__ vin, const float* __restrict__ wbar,
    short* __restrict__ qws, short* __restrict__ kws, short* __restrict__ vtws) {
    __shared__ float xl[536 * L_];
    int blk = blockIdx.x;            // grid = 3*8*16 = 384
    int cg  = blk & 15;
    int b   = (blk >> 4) & 7;
    int tz  = blk >> 7;
    const float* x = (tz == 0) ? qin : (tz == 1) ? kin : vin;

    const float4* xb4 = (const float4*)(x + b * DM_ * L_);
    float4* xl4 = (float4*)xl;
    for (int i = threadIdx.x; i < DM_ * L_ / 4; i += 256) xl4[i] = xb4[i];
    for (int i = DM_ * L_ + threadIdx.x; i < 536 * L_; i += 256) xl[i] = 0.f;

    int c_local = threadIdx.x >> 3;
    int plane   = threadIdx.x & 7;
    int c       = cg * 32 + c_local;
    float wreg[EFF_];
    const float4* wb4 = (const float4*)(wbar + ((size_t)tz * DM_ + c) * EFF_);
    #pragma unroll
    for (int i = 0; i < 8; ++i) {
        float4 t4 = wb4[i];
        wreg[4*i+0] = t4.x; wreg[4*i+1] = t4.y;
        wreg[4*i+2] = t4.z; wreg[4*i+3] = t4.w;
    }
    __syncthreads();

    for (int m = 0; m < 32; ++m) {
        int pg  = plane + 8 * m;
        int h2b = pg >> 4;
        int l   = pg & 15;
        float acc[4] = {0.f, 0.f, 0.f, 0.f};
        #pragma unroll
        for (int k = 0; k < 56; ++k) {
            float xv = xl[(h2b * 32 + k) * L_ + l];
            #pragma unroll
            for (int d = 0; d < 4; ++d) {
                int t = k - 8 * d;
                if (t >= 0 && t < EFF_) acc[d] = fmaf(xv, wreg[t], acc[d]);
            }
        }
        #pragma unroll
        for (int d = 0; d < 4; ++d) {
            int h2 = h2b * 4 + d;
            if (h2 < H2_) {
                int f    = c * S_ + h2 * L_ + l;
                int s    = f >> 9;
                int head = (f >> 6) & 7;
                int dh   = f & 63;
                int bh   = b * H_ + head;
                short bv = (short)f2bfu(acc[d]);
                if (tz == 0)      qws[((size_t)bh * S_ + s) * D_ + dh] = bv;
                else if (tz == 1) kws[((size_t)bh * S_ + s) * D_ + dh] = bv;
                else              vtws[((size_t)bh * D_ + dh) * SP_ + s] = bv;
            }
        }
    }
}

// ---------------------------------------------------------------------------
// Kernel 3: attention, PAIRED q-tiles (L2-read halving on R6 structure).
// One block per (bh, q-tile PAIR); 4 waves own key quarters (16/15/15/15).
// Each wave computes BOTH q-tiles of the pair from ONE K load (pass A) and
// ONE V load (pass B): per-block L2 read traffic is halved vs R6.
// Pair 30's second tile (qt=61) is computed-but-not-stored (clamped Q).
// ---------------------------------------------------------------------------
__global__ __launch_bounds__(256) void attn_kernel(
    const short* __restrict__ qws, const short* __restrict__ kws,
    const short* __restrict__ vtws, const float* __restrict__ w_out,
    const float* __restrict__ b_out, float* __restrict__ out) {
    __shared__ short plds[4][2][16 * 40];     // per-wave,per-tile P (10.2 KB)
    __shared__ float olds[2][3][16 * OSTR];   // per-tile partial O (26.1 KB)
    __shared__ float sums[4][2][16];

    int w    = threadIdx.x >> 6;
    int lane = threadIdx.x & 63;
    int l16  = lane & 15;
    int g    = lane >> 4;

    // XCD swizzle: xcd = blk%8 hosts bh in {xcd, xcd+8, ..., xcd+56}
    int blk = blockIdx.x;       // 0..1983
    int xcd = blk & 7;
    int j   = blk >> 3;         // 0..247
    int bh  = xcd + 8 * (j / 31);
    int pr  = j % 31;           // pair 0..30
    int qtA = pr * 2;           // 0..60
    int qtB = qtA + 1;          // 1..61 (61 = phantom)
    bool validB = (qtB < H2_);  // block-uniform
    int qtBc = validB ? qtB : qtA;
    int sA = qtA * 16, sB = qtB * 16;

    int t0 = (w == 0) ? 0 : 16 + (w - 1) * 15;   // 0,16,31,46
    int nt = (w == 0) ? 16 : 15;

    unsigned ppA[16][2], ppB[16][2];   // packed bf16 exp-scores (registers)

    const short* qpA = qws + ((size_t)bh * S_ + sA + l16) * D_ + g * 8;
    const short* qpB = qws + ((size_t)bh * S_ + qtBc * 16 + l16) * D_ + g * 8;
    bf16x8 qa0 = *(const bf16x8*)qpA;
    bf16x8 qa1 = *(const bf16x8*)(qpA + 32);
    bf16x8 qb0 = *(const bf16x8*)qpB;
    bf16x8 qb1 = *(const bf16x8*)(qpB + 32);
    const short* kb0 = kws + ((size_t)bh * S_ + t0 * 16 + l16) * D_ + g * 8;

    // ---- pass A: one K load -> QK for BOTH tiles ----
    float sA0 = 0.f, sA1 = 0.f, sA2 = 0.f, sA3 = 0.f;
    float sB0 = 0.f, sB1 = 0.f, sB2 = 0.f, sB3 = 0.f;
    #pragma unroll
    for (int ct = 0; ct < 16; ++ct) {
        if (ct < nt) {                       // wave-uniform guard
            const short* kb = kb0 + (size_t)ct * 16 * D_;
            bf16x8 k0 = *(const bf16x8*)kb;
            bf16x8 k1 = *(const bf16x8*)(kb + 32);
            f32x4 accA = {0.f, 0.f, 0.f, 0.f};
            accA = __builtin_amdgcn_mfma_f32_16x16x32_bf16(k0, qa0, accA, 0, 0, 0);
            accA = __builtin_amdgcn_mfma_f32_16x16x32_bf16(k1, qa1, accA, 0, 0, 0);
            f32x4 accB = {0.f, 0.f, 0.f, 0.f};
            accB = __builtin_amdgcn_mfma_f32_16x16x32_bf16(k0, qb0, accB, 0, 0, 0);
            accB = __builtin_amdgcn_mfma_f32_16x16x32_bf16(k1, qb1, accB, 0, 0, 0);
            float a0 = __expf(accA[0] * 0.125f);
            float a1 = __expf(accA[1] * 0.125f);
            float a2 = __expf(accA[2] * 0.125f);
            float a3 = __expf(accA[3] * 0.125f);
            sA0 += a0; sA1 += a1; sA2 += a2; sA3 += a3;
            ppA[ct][0] = packbf(a0, a1);
            ppA[ct][1] = packbf(a2, a3);
            float b0 = __expf(accB[0] * 0.125f);
            float b1 = __expf(accB[1] * 0.125f);
            float b2 = __expf(accB[2] * 0.125f);
            float b3 = __expf(accB[3] * 0.125f);
            sB0 += b0; sB1 += b1; sB2 += b2; sB3 += b3;
            ppB[ct][0] = packbf(b0, b1);
            ppB[ct][1] = packbf(b2, b3);
        }
    }
    float sumA = (sA0 + sA1) + (sA2 + sA3);
    sumA += __shfl_xor(sumA, 16);
    sumA += __shfl_xor(sumA, 32);
    float sumB = (sB0 + sB1) + (sB2 + sB3);
    sumB += __shfl_xor(sumB, 16);
    sumB += __shfl_xor(sumB, 32);
    if (lane < 16) { sums[w][0][l16] = sumA; sums[w][1][l16] = sumB; }
    __syncthreads();
    float invA = 1.f / ((sums[0][0][l16] + sums[1][0][l16]) +
                        (sums[2][0][l16] + sums[3][0][l16]));
    float invB = 1.f / ((sums[0][1][l16] + sums[1][1][l16]) +
                        (sums[2][1][l16] + sums[3][1][l16]));

    f32x4 oA0 = {0.f,0.f,0.f,0.f}, oA1 = {0.f,0.f,0.f,0.f};
    f32x4 oA2 = {0.f,0.f,0.f,0.f}, oA3 = {0.f,0.f,0.f,0.f};
    f32x4 oB0 = {0.f,0.f,0.f,0.f}, oB1 = {0.f,0.f,0.f,0.f};
    f32x4 oB2 = {0.f,0.f,0.f,0.f}, oB3 = {0.f,0.f,0.f,0.f};

    float* arowA = out + XOFF + ((size_t)bh * S_ + sA + l16) * S_;
    float* arowB = out + XOFF + ((size_t)bh * S_ + sB + l16) * S_;
    short* plA = &plds[w][0][0];
    short* plB = &plds[w][1][0];
    const short* vrow = vtws + ((size_t)bh * D_ + l16) * SP_ + g * 8;

    // ---- pass B: one V load -> PV for BOTH tiles ----
    int nc = (w == 0) ? 8 : 7;
    #pragma unroll
    for (int c = 0; c < 8; ++c) {
        if (c < nc) {
            #pragma unroll
            for (int t = 0; t < 2; ++t) {
                int lt = 2 * c + t;            // static after unroll
                int gt = t0 + lt;
                unsigned uA0 = ppA[lt][0], uA1 = ppA[lt][1];
                f32x4 pvA = { bflo(uA0) * invA, bfhi(uA0) * invA,
                              bflo(uA1) * invA, bfhi(uA1) * invA };
                __builtin_nontemporal_store(pvA, (f32x4*)(arowA + gt * 16 + g * 4));
                uint2 upA = {uA0, uA1};
                *(uint2*)(void*)(plA + l16 * 40 + t * 16 + g * 4) = upA;
                unsigned uB0 = ppB[lt][0], uB1 = ppB[lt][1];
                if (validB) {
                    f32x4 pvB = { bflo(uB0) * invB, bfhi(uB0) * invB,
                                  bflo(uB1) * invB, bfhi(uB1) * invB };
                    __builtin_nontemporal_store(pvB, (f32x4*)(arowB + gt * 16 + g * 4));
                }
                uint2 upB = {uB0, uB1};
                *(uint2*)(void*)(plB + l16 * 40 + t * 16 + g * 4) = upB;
            }
            __threadfence_block();
            bf16x8 paA = *(const bf16x8*)(plA + l16 * 40 + g * 8);
            bf16x8 paB = *(const bf16x8*)(plB + l16 * 40 + g * 8);
            const short* vb = vrow + t0 * 16 + c * 32;
            bf16x8 v0 = *(const bf16x8*)(vb);
            bf16x8 v1 = *(const bf16x8*)(vb + 16 * SP_);
            bf16x8 v2 = *(const bf16x8*)(vb + 32 * SP_);
            bf16x8 v3 = *(const bf16x8*)(vb + 48 * SP_);
            oA0 = __builtin_amdgcn_mfma_f32_16x16x32_bf16(paA, v0, oA0, 0, 0, 0);
            oA1 = __builtin_amdgcn_mfma_f32_16x16x32_bf16(paA, v1, oA1, 0, 0, 0);
            oA2 = __builtin_amdgcn_mfma_f32_16x16x32_bf16(paA, v2, oA2, 0, 0, 0);
            oA3 = __builtin_amdgcn_mfma_f32_16x16x32_bf16(paA, v3, oA3, 0, 0, 0);
            oB0 = __builtin_amdgcn_mfma_f32_16x16x32_bf16(paB, v0, oB0, 0, 0, 0);
            oB1 = __builtin_amdgcn_mfma_f32_16x16x32_bf16(paB, v1, oB1, 0, 0, 0);
            oB2 = __builtin_amdgcn_mfma_f32_16x16x32_bf16(paB, v2, oB2, 0, 0, 0);
            oB3 = __builtin_amdgcn_mfma_f32_16x16x32_bf16(paB, v3, oB3, 0, 0, 0);
        }
    }

    // ---- tail: odd 15th tile for w>0, phantom zero-P upper half ----
    if (w != 0) {
        unsigned uA0 = ppA[14][0], uA1 = ppA[14][1];
        f32x4 pvA = { bflo(uA0) * invA, bfhi(uA0) * invA,
                      bflo(uA1) * invA, bfhi(uA1) * invA };
        __builtin_nontemporal_store(pvA, (f32x4*)(arowA + (t0 + 14) * 16 + g * 4));
        uint2 upA = {uA0, uA1};
        uint2 zz = {0u, 0u};
        *(uint2*)(void*)(plA + l16 * 40 + g * 4) = upA;
        *(uint2*)(void*)(plA + l16 * 40 + 16 + g * 4) = zz;
        unsigned uB0 = ppB[14][0], uB1 = ppB[14][1];
        if (validB) {
            f32x4 pvB = { bflo(uB0) * invB, bfhi(uB0) * invB,
                          bflo(uB1) * invB, bfhi(uB1) * invB };
            __builtin_nontemporal_store(pvB, (f32x4*)(arowB + (t0 + 14) * 16 + g * 4));
        }
        uint2 upB = {uB0, uB1};
        *(uint2*)(void*)(plB + l16 * 40 + g * 4) = upB;
        *(uint2*)(void*)(plB + l16 * 40 + 16 + g * 4) = zz;
        __threadfence_block();
        bf16x8 paA = *(const bf16x8*)(plA + l16 * 40 + g * 8);
        bf16x8 paB = *(const bf16x8*)(plB + l16 * 40 + g * 8);
        const short* vb = vrow + t0 * 16 + 224;
        bf16x8 v0 = *(const bf16x8*)(vb);
        bf16x8 v1 = *(const bf16x8*)(vb + 16 * SP_);
        bf16x8 v2 = *(const bf16x8*)(vb + 32 * SP_);
        bf16x8 v3 = *(const bf16x8*)(vb + 48 * SP_);
        oA0 = __builtin_amdgcn_mfma_f32_16x16x32_bf16(paA, v0, oA0, 0, 0, 0);
        oA1 = __builtin_amdgcn_mfma_f32_16x16x32_bf16(paA, v1, oA1, 0, 0, 0);
        oA2 = __builtin_amdgcn_mfma_f32_16x16x32_bf16(paA, v2, oA2, 0, 0, 0);
        oA3 = __builtin_amdgcn_mfma_f32_16x16x32_bf16(paA, v3, oA3, 0, 0, 0);
        oB0 = __builtin_amdgcn_mfma_f32_16x16x32_bf16(paB, v0, oB0, 0, 0, 0);
        oB1 = __builtin_amdgcn_mfma_f32_16x16x32_bf16(paB, v1, oB1, 0, 0, 0);
        oB2 = __builtin_amdgcn_mfma_f32_16x16x32_bf16(paB, v2, oB2, 0, 0, 0);
        oB3 = __builtin_amdgcn_mfma_f32_16x16x32_bf16(paB, v3, oB3, 0, 0, 0);
    }

    // ---- waves 0..2 publish raw partial O for both tiles ----
    if (w != 3) {
        #pragma unroll
        for (int i = 0; i < 4; ++i) {
            int q = g * 4 + i;
            float* obA = &olds[0][w][0];
            obA[q * OSTR +  0 + l16] = oA0[i];
            obA[q * OSTR + 16 + l16] = oA1[i];
            obA[q * OSTR + 32 + l16] = oA2[i];
            obA[q * OSTR + 48 + l16] = oA3[i];
            float* obB = &olds[1][w][0];
            obB[q * OSTR +  0 + l16] = oB0[i];
            obB[q * OSTR + 16 + l16] = oB1[i];
            obB[q * OSTR + 32 + l16] = oB2[i];
            obB[q * OSTR + 48 + l16] = oB3[i];
        }
    }
    __syncthreads();

    // ---- w3 combines, normalizes (deferred inv), writes x for both ----
    if (w == 3) {
        float wo = w_out[0], bo = b_out[0];
        int b = bh >> 3, hh = bh & 7;
        #pragma unroll
        for (int i = 0; i < 4; ++i) {
            int q = g * 4 + i;
            float ivA = __shfl(invA, q) * wo;
            float* xrA = out + ((size_t)b * S_ + sA + q) * DM_ + hh * D_ + l16;
            int o = q * OSTR + l16;
            xrA[0]  = (oA0[i] + olds[0][0][o +  0] + olds[0][1][o +  0] + olds[0][2][o +  0]) * ivA + bo;
            xrA[16] = (oA1[i] + olds[0][0][o + 16] + olds[0][1][o + 16] + olds[0][2][o + 16]) * ivA + bo;
            xrA[32] = (oA2[i] + olds[0][0][o + 32] + olds[0][1][o + 32] + olds[0][2][o + 32]) * ivA + bo;
            xrA[48] = (oA3[i] + olds[0][0][o + 48] + olds[0][1][o + 48] + olds[0][2][o + 48]) * ivA + bo;
            if (validB) {
                float ivB = __shfl(invB, q) * wo;
                float* xrB = out + ((size_t)b * S_ + sB + q) * DM_ + hh * D_ + l16;
                xrB[0]  = (oB0[i] + olds[1][0][o +  0] + olds[1][1][o +  0] + olds[1][2][o +  0]) * ivB + bo;
                xrB[16] = (oB1[i] + olds[1][0][o + 16] + olds[1][1][o + 16] + olds[1][2][o + 16]) * ivB + bo;
                xrB[32] = (oB2[i] + olds[1][0][o + 32] + olds[1][1][o + 32] + olds[1][2][o + 32]) * ivB + bo;
                xrB[48] = (oB3[i] + olds[1][0][o + 48] + olds[1][1][o + 48] + olds[1][2][o + 48]) * ivB + bo;
            }
        }
    }
}

// ---------------------------------------------------------------------------
extern "C" void kernel_launch(void* const* d_in, const int* in_sizes, int n_in,
                              void* d_out, int out_size, void* d_ws, size_t ws_size,
                              hipStream_t stream) {
    const float* q   = (const float*)d_in[0];
    const float* k   = (const float*)d_in[1];
    const float* v   = (const float*)d_in[2];
    const float* wq  = (const float*)d_in[3];
    const float* wk  = (const float*)d_in[4];
    const float* wv  = (const float*)d_in[5];
    const float* wo  = (const float*)d_in[6];
    const float* bo  = (const float*)d_in[7];

    char* ws = (char*)d_ws;
    float* wbar = (float*)ws;
    short* qws  = (short*)(ws + 196608);
    short* kws  = qws + (size_t)BH_ * S_ * D_;
    short* vtws = kws + (size_t)BH_ * S_ * D_;

    // 192 blocks compute wbar; 256 more zero the V^T pad columns
    wbar_kernel<<<448, 256, 0, stream>>>(wq, wk, wv, wbar, vtws);
    proj_kernel<<<384, 256, 0, stream>>>(q, k, v, wbar, qws, kws, vtws);
    attn_kernel<<<BH_ * 31, 256, 0, stream>>>(qws, kws, vtws, wo, bo,
                                              (float*)d_out);
}